// Round 1
// baseline (268.195 us; speedup 1.0000x reference)
//
#include <hip/hip_runtime.h>

// Problem constants (fixed by reference):
//   N=16384 spatial, R=16 feat, P=4096 blocks, T=64 out-feat, B=8 batch
#define C_N 16384
#define C_R 16
#define C_P 4096
#define C_B 8

// One wave (64 lanes) per block p; 4 waves per workgroup -> 4 p's per block.
// Lane = output column o in [0,64). Weight reads: wave reads W[p][i][o] for
// o=lane -> contiguous 256 B, each weight byte read exactly once from HBM.
// x tile staged (butterfly-permuted) into LDS; compute reads are wave-uniform
// broadcasts (conflict-free).
__global__ __launch_bounds__(256)
void butterfly_local_conv(const float* __restrict__ x,
                          const float* __restrict__ Wrr,
                          const float* __restrict__ Wri,
                          const float* __restrict__ Wir,
                          const float* __restrict__ Wii,
                          const int*   __restrict__ perm,
                          float* __restrict__ out)
{
    // lds_x[p_local][c][b][i], i = s*16 + r  (16 KB)
    __shared__ float lds_x[4][2][C_B][64];

    const int tid    = threadIdx.x;
    const int p_base = blockIdx.x * 4;

    // ---- stage permuted x into LDS: one (p_local,c,b,s) row of 16 floats per thread
    {
        const int pl  = tid >> 6;          // 0..3
        const int rem = tid & 63;
        const int c   = rem >> 5;          // 0..1
        const int b   = (rem >> 2) & 7;    // 0..7
        const int s   = rem & 3;           // 0..3
        const int p   = p_base + pl;
        const int n   = perm[4 * p + s];
        const float4* src = (const float4*)(x + (((size_t)(b * 2 + c)) * C_N + n) * C_R);
        float4* dst = (float4*)(&lds_x[pl][c][b][s * 16]);
        dst[0] = src[0];
        dst[1] = src[1];
        dst[2] = src[2];
        dst[3] = src[3];
    }
    __syncthreads();

    const int w = tid >> 6;   // wave id == p_local
    const int o = tid & 63;   // output column
    const int p = p_base + w;

    float acc_re[C_B], acc_im[C_B];
    #pragma unroll
    for (int b = 0; b < C_B; ++b) { acc_re[b] = 0.0f; acc_im[b] = 0.0f; }

    const size_t wbase = (size_t)p * 64 * 64 + o;
    const float* __restrict__ wrr_p = Wrr + wbase;
    const float* __restrict__ wri_p = Wri + wbase;
    const float* __restrict__ wir_p = Wir + wbase;
    const float* __restrict__ wii_p = Wii + wbase;

    // K-loop over i (4R = 64), chunked by 4 so x comes as ds_read_b128.
    for (int i0 = 0; i0 < 64; i0 += 4) {
        float wrr[4], wri[4], wir[4], wii[4];
        #pragma unroll
        for (int k = 0; k < 4; ++k) {
            const int off = (i0 + k) * 64;
            wrr[k] = wrr_p[off];
            wri[k] = wri_p[off];
            wir[k] = wir_p[off];
            wii[k] = wii_p[off];
        }
        #pragma unroll
        for (int b = 0; b < C_B; ++b) {
            const float4 xr4 = *(const float4*)(&lds_x[w][0][b][i0]);
            const float4 xi4 = *(const float4*)(&lds_x[w][1][b][i0]);
            acc_re[b] = fmaf(xr4.x, wrr[0], acc_re[b]);
            acc_re[b] = fmaf(xi4.x, wri[0], acc_re[b]);
            acc_im[b] = fmaf(xr4.x, wir[0], acc_im[b]);
            acc_im[b] = fmaf(xi4.x, wii[0], acc_im[b]);

            acc_re[b] = fmaf(xr4.y, wrr[1], acc_re[b]);
            acc_re[b] = fmaf(xi4.y, wri[1], acc_re[b]);
            acc_im[b] = fmaf(xr4.y, wir[1], acc_im[b]);
            acc_im[b] = fmaf(xi4.y, wii[1], acc_im[b]);

            acc_re[b] = fmaf(xr4.z, wrr[2], acc_re[b]);
            acc_re[b] = fmaf(xi4.z, wri[2], acc_re[b]);
            acc_im[b] = fmaf(xr4.z, wir[2], acc_im[b]);
            acc_im[b] = fmaf(xi4.z, wii[2], acc_im[b]);

            acc_re[b] = fmaf(xr4.w, wrr[3], acc_re[b]);
            acc_re[b] = fmaf(xi4.w, wri[3], acc_re[b]);
            acc_im[b] = fmaf(xr4.w, wir[3], acc_im[b]);
            acc_im[b] = fmaf(xi4.w, wii[3], acc_im[b]);
        }
    }

    // ---- epilogue: out[b][c][4p + o/16][o%16] == flat (b*2+c)*N*R + p*64 + o
    #pragma unroll
    for (int b = 0; b < C_B; ++b) {
        const size_t base = (size_t)p * 64 + o;
        out[((size_t)(b * 2 + 0)) * (C_N * C_R) + base] = acc_re[b];
        out[((size_t)(b * 2 + 1)) * (C_N * C_R) + base] = acc_im[b];
    }
}

extern "C" void kernel_launch(void* const* d_in, const int* in_sizes, int n_in,
                              void* d_out, int out_size, void* d_ws, size_t ws_size,
                              hipStream_t stream) {
    const float* x    = (const float*)d_in[0];
    const float* Wrr  = (const float*)d_in[1];
    const float* Wri  = (const float*)d_in[2];
    const float* Wir  = (const float*)d_in[3];
    const float* Wii  = (const float*)d_in[4];
    const int*   perm = (const int*)d_in[5];
    float* out = (float*)d_out;

    // P = 4096 blocks, 4 per workgroup -> 1024 workgroups of 256 threads.
    butterfly_local_conv<<<dim3(C_P / 4), dim3(256), 0, stream>>>(
        x, Wrr, Wri, Wir, Wii, perm, out);
}